// Round 6
// baseline (235.117 us; speedup 1.0000x reference)
//
#include <hip/hip_runtime.h>
#include <math.h>

#define NB    4
#define NCLS  5
#define NSHOT 5
#define NQ    75
#define CH    640
#define HW    100
#define SLICE (CH*HW)          // 64000
#define TEMP_INV 4.0f
#define EPSN  1e-12f

typedef float f32x4 __attribute__((ext_vector_type(4)));
typedef float f32x2 __attribute__((ext_vector_type(2)));

// workspace float offsets
#define OFF_PROTO 0            // 1,280,000
#define OFF_PINV  1280000      // 2,000
#define OFF_PBAR  1282000      // 12,800
#define OFF_QINV  1294800      // 30,000
#define OFF_QBAR  1324800      // 192,000
#define OFF_AP    1516800      // 150,000
#define OFF_AQ    1666800      // 150,000

// K1: proto[bn, cc, i] = mean over K shots of fspt
__global__ void k_proto(const float* __restrict__ fspt, float* __restrict__ proto) {
    int v = blockIdx.x * 256 + threadIdx.x;      // float4 index, 320000 total
    if (v >= (NB*NCLS*SLICE)/4) return;
    int p  = v * 4;
    int bn = p / SLICE;
    size_t base = (size_t)bn * NSHOT * SLICE + (p - bn * SLICE);
    f32x4 a = *reinterpret_cast<const f32x4*>(fspt + base);
    for (int k = 1; k < NSHOT; k++)
        a += *reinterpret_cast<const f32x4*>(fspt + base + (size_t)k * SLICE);
    a *= 0.2f;
    *reinterpret_cast<f32x4*>(proto + p) = a;
}

// K2: per-slice stats for proto (blk<20) and fqry (blk>=20).
__global__ void k_stats(const float* __restrict__ proto, const float* __restrict__ fqry,
                        float* __restrict__ pinv, float* __restrict__ pbar,
                        float* __restrict__ qinv, float* __restrict__ qbar) {
    __shared__ float inv_s[HW];
    __shared__ float part_s[256];
    int blk = blockIdx.x;
    bool isP = blk < NB * NCLS;
    int s = isP ? blk : blk - NB * NCLS;
    const float* base = (isP ? proto : fqry) + (size_t)s * SLICE;
    float* inv = (isP ? pinv : qinv) + s * HW;
    float* bar = (isP ? pbar : qbar) + s * CH;
    int t = threadIdx.x;

    float partial = 0.f;
    if (t < 200) {
        int i  = (t < 100) ? t : t - 100;
        int c0 = (t < 100) ? 0 : CH / 2;
        const float* p = base + (size_t)c0 * HW + i;
        #pragma unroll 8
        for (int cc = 0; cc < CH / 2; cc++) { float x = p[cc * HW]; partial += x * x; }
    }
    part_s[t] = partial;
    __syncthreads();
    if (t < HW) {
        float iv = 1.0f / fmaxf(sqrtf(part_s[t] + part_s[t + 100]), EPSN);
        inv_s[t] = iv;
        inv[t] = iv;
    }
    __syncthreads();
    for (int cc = t; cc < CH; cc += 256) {
        float acc = 0.f;
        const f32x4* r = reinterpret_cast<const f32x4*>(base + (size_t)cc * HW);
        #pragma unroll
        for (int i4 = 0; i4 < HW / 4; i4++) {
            f32x4 x = r[i4];
            acc += x.x * inv_s[i4*4] + x.y * inv_s[i4*4+1] + x.z * inv_s[i4*4+2] + x.w * inv_s[i4*4+3];
        }
        bar[cc] = acc * (1.0f / HW);
    }
}

// K3: fused attention maps, 128 threads/block.
// blk<500 -> ap panel (bn,qg): 15 q's. blk>=500 -> aq panel (bq): 5 n's.
// wave w (0/1) owns c-half w; lanes l<50 own i-pair (2l, 2l+1).
__global__ void k_att(const float* __restrict__ proto, const float* __restrict__ fqry,
                      const float* __restrict__ pinv, const float* __restrict__ pbar,
                      const float* __restrict__ qinv, const float* __restrict__ qbar,
                      float* __restrict__ ap, float* __restrict__ aq) {
    __shared__ __align__(16) float smem[12704];   // 50.8 KB, carved per path
    int blk = blockIdx.x;
    int t = threadIdx.x;
    int w = t >> 6, l = t & 63;

    if (blk < NB * NCLS * 5) {
        // ---- ap panel ----
        float* qb_s   = smem;             // 15*CH = 9600
        float* part_s = smem + 9600;      // 15*200 = 3000
        float* piv_s  = smem + 12600;     // 100
        int bn = blk / 5;
        int qg = blk - bn * 5;
        int b  = bn / NCLS;

        const f32x4* qsrc = reinterpret_cast<const f32x4*>(qbar + (size_t)(b * NQ + qg * 15) * CH);
        f32x4* qdst = reinterpret_cast<f32x4*>(qb_s);
        for (int k = t; k < 15 * CH / 4; k += 128) qdst[k] = qsrc[k];
        if (t < HW) piv_s[t] = pinv[bn * HW + t] * TEMP_INV;
        __syncthreads();

        if (l < 50) {
            int c0 = w * (CH / 2);
            const float* p = proto + (size_t)bn * SLICE + (size_t)c0 * HW + 2 * l;
            const float* qb0 = qb_s + c0;
            float accA[15], accB[15];
            #pragma unroll
            for (int qq = 0; qq < 15; qq++) { accA[qq] = 0.f; accB[qq] = 0.f; }
            for (int c4 = 0; c4 < (CH / 2) / 4; c4++) {
                f32x2 p0 = *reinterpret_cast<const f32x2*>(p + (c4*4+0) * HW);
                f32x2 p1 = *reinterpret_cast<const f32x2*>(p + (c4*4+1) * HW);
                f32x2 p2 = *reinterpret_cast<const f32x2*>(p + (c4*4+2) * HW);
                f32x2 p3 = *reinterpret_cast<const f32x2*>(p + (c4*4+3) * HW);
                #pragma unroll
                for (int qq = 0; qq < 15; qq++) {
                    f32x4 q4 = *reinterpret_cast<const f32x4*>(qb0 + qq * CH + c4 * 4);
                    accA[qq] += p0.x*q4.x + p1.x*q4.y + p2.x*q4.z + p3.x*q4.w;
                    accB[qq] += p0.y*q4.x + p1.y*q4.y + p2.y*q4.z + p3.y*q4.w;
                }
            }
            #pragma unroll
            for (int qq = 0; qq < 15; qq++) {
                f32x2 v; v.x = accA[qq]; v.y = accB[qq];
                *reinterpret_cast<f32x2*>(part_s + qq * 200 + w * 100 + 2 * l) = v;
            }
        }
        __syncthreads();

        for (int qq = w; qq < 15; qq += 2) {
            float sv0 = (part_s[qq*200 + l] + part_s[qq*200 + l + 100]) * piv_s[l];
            float sv1 = (l < 36) ? (part_s[qq*200 + l + 64] + part_s[qq*200 + l + 164]) * piv_s[l + 64] : -INFINITY;
            float m = fmaxf(sv0, sv1);
            #pragma unroll
            for (int o = 32; o >= 1; o >>= 1) m = fmaxf(m, __shfl_xor(m, o, 64));
            float e0 = __expf(sv0 - m);
            float e1 = (l < 36) ? __expf(sv1 - m) : 0.f;
            float sm = e0 + e1;
            #pragma unroll
            for (int o = 32; o >= 1; o >>= 1) sm += __shfl_xor(sm, o, 64);
            float inv = 1.0f / sm;
            int bqn = (b * NQ + qg * 15 + qq) * NCLS + (bn - b * NCLS);
            float* dst = ap + (size_t)bqn * HW;
            dst[l] = e0 * inv + 1.0f;
            if (l < 36) dst[l + 64] = e1 * inv + 1.0f;
        }
    } else {
        // ---- aq panel ----
        float* pb_s   = smem;             // NCLS*CH = 3200
        float* part_s = smem + 3200;      // NCLS*200 = 1000
        float* qiv_s  = smem + 4200;      // 100
        int bq = blk - NB * NCLS * 5;
        int b  = bq / NQ;

        const f32x4* psrc = reinterpret_cast<const f32x4*>(pbar + (size_t)b * NCLS * CH);
        f32x4* pdst = reinterpret_cast<f32x4*>(pb_s);
        for (int k = t; k < NCLS * CH / 4; k += 128) pdst[k] = psrc[k];
        if (t < HW) qiv_s[t] = qinv[bq * HW + t] * TEMP_INV;
        __syncthreads();

        if (l < 50) {
            int c0 = w * (CH / 2);
            const float* p = fqry + (size_t)bq * SLICE + (size_t)c0 * HW + 2 * l;
            const float* pb0 = pb_s + c0;
            float accA[NCLS], accB[NCLS];
            #pragma unroll
            for (int n = 0; n < NCLS; n++) { accA[n] = 0.f; accB[n] = 0.f; }
            for (int c4 = 0; c4 < (CH / 2) / 4; c4++) {
                f32x2 p0 = *reinterpret_cast<const f32x2*>(p + (c4*4+0) * HW);
                f32x2 p1 = *reinterpret_cast<const f32x2*>(p + (c4*4+1) * HW);
                f32x2 p2 = *reinterpret_cast<const f32x2*>(p + (c4*4+2) * HW);
                f32x2 p3 = *reinterpret_cast<const f32x2*>(p + (c4*4+3) * HW);
                #pragma unroll
                for (int n = 0; n < NCLS; n++) {
                    f32x4 q4 = *reinterpret_cast<const f32x4*>(pb0 + n * CH + c4 * 4);
                    accA[n] += p0.x*q4.x + p1.x*q4.y + p2.x*q4.z + p3.x*q4.w;
                    accB[n] += p0.y*q4.x + p1.y*q4.y + p2.y*q4.z + p3.y*q4.w;
                }
            }
            #pragma unroll
            for (int n = 0; n < NCLS; n++) {
                f32x2 v; v.x = accA[n]; v.y = accB[n];
                *reinterpret_cast<f32x2*>(part_s + n * 200 + w * 100 + 2 * l) = v;
            }
        }
        __syncthreads();

        for (int n = w; n < NCLS; n += 2) {
            float sv0 = (part_s[n*200 + l] + part_s[n*200 + l + 100]) * qiv_s[l];
            float sv1 = (l < 36) ? (part_s[n*200 + l + 64] + part_s[n*200 + l + 164]) * qiv_s[l + 64] : -INFINITY;
            float m = fmaxf(sv0, sv1);
            #pragma unroll
            for (int o = 32; o >= 1; o >>= 1) m = fmaxf(m, __shfl_xor(m, o, 64));
            float e0 = __expf(sv0 - m);
            float e1 = (l < 36) ? __expf(sv1 - m) : 0.f;
            float sm = e0 + e1;
            #pragma unroll
            for (int o = 32; o >= 1; o >>= 1) sm += __shfl_xor(sm, o, 64);
            float inv = 1.0f / sm;
            int bqn = bq * NCLS + n;
            float* dst = aq + (size_t)bqn * HW;
            dst[l] = e0 * inv + 1.0f;
            if (l < 36) dst[l + 64] = e1 * inv + 1.0f;
        }
    }
}

// K4: fused output writer, register-held input, broadcast loop.
// blk<2500: out0 (bn, chunk): hold proto f4, loop 75 q.
// blk>=2500: out1 (bq, chunk): hold fqry f4, loop 5 n.
// 128 threads, chunk = 512 floats (125 chunks per slice).
__global__ void k_outs(const float* __restrict__ proto, const float* __restrict__ fqry,
                       const float* __restrict__ ap, const float* __restrict__ aq,
                       float* __restrict__ out) {
    const size_t OUT1 = (size_t)NB * NQ * NCLS * SLICE; // 96,000,000
    int blk = blockIdx.x;
    int t = threadIdx.x;

    if (blk < NB * NCLS * 125) {
        int bn = blk / 125;
        int ch = blk - bn * 125;
        int off = ch * 512 + t * 4;
        int i = off % HW;
        int b = bn / NCLS, n = bn - b * NCLS;
        f32x4 pv = *reinterpret_cast<const f32x4*>(proto + (size_t)bn * SLICE + off);
        const float* apb = ap + (size_t)(b * NQ * NCLS + n) * HW + i;
        float* ob = out + (size_t)(b * NQ * NCLS + n) * SLICE + off;
        #pragma unroll 5
        for (int q = 0; q < NQ; q++) {
            f32x4 av = *reinterpret_cast<const f32x4*>(apb + (size_t)q * NCLS * HW);
            f32x4 o = pv * av;
            __builtin_nontemporal_store(o, reinterpret_cast<f32x4*>(ob + (size_t)q * NCLS * SLICE));
        }
    } else {
        int bb = blk - NB * NCLS * 125;
        int bq = bb / 125;
        int ch = bb - bq * 125;
        int off = ch * 512 + t * 4;
        int i = off % HW;
        f32x4 qv = *reinterpret_cast<const f32x4*>(fqry + (size_t)bq * SLICE + off);
        const float* aqb = aq + (size_t)bq * NCLS * HW + i;
        float* ob = out + OUT1 + (size_t)bq * NCLS * SLICE + off;
        #pragma unroll
        for (int n = 0; n < NCLS; n++) {
            f32x4 av = *reinterpret_cast<const f32x4*>(aqb + n * HW);
            f32x4 o = qv * av;
            __builtin_nontemporal_store(o, reinterpret_cast<f32x4*>(ob + (size_t)n * SLICE));
        }
    }
}

extern "C" void kernel_launch(void* const* d_in, const int* in_sizes, int n_in,
                              void* d_out, int out_size, void* d_ws, size_t ws_size,
                              hipStream_t stream) {
    const float* fspt = (const float*)d_in[0];
    const float* fqry = (const float*)d_in[1];
    float* ws  = (float*)d_ws;
    float* out = (float*)d_out;

    float* proto = ws + OFF_PROTO;
    float* pinv  = ws + OFF_PINV;
    float* pbar  = ws + OFF_PBAR;
    float* qinv  = ws + OFF_QINV;
    float* qbar  = ws + OFF_QBAR;
    float* ap    = ws + OFF_AP;
    float* aq    = ws + OFF_AQ;

    k_proto<<<1250, 256, 0, stream>>>(fspt, proto);
    k_stats<<<NB * NCLS + NB * NQ, 256, 0, stream>>>(proto, fqry, pinv, pbar, qinv, qbar);
    k_att<<<NB * NCLS * 5 + NB * NQ, 128, 0, stream>>>(proto, fqry, pinv, pbar, qinv, qbar, ap, aq);
    k_outs<<<NB * NCLS * 125 + NB * NQ * 125, 128, 0, stream>>>(proto, fqry, ap, aq, out);
}